// Round 1
// baseline (841.664 us; speedup 1.0000x reference)
//
#include <hip/hip_runtime.h>
#include <math.h>

#define NN 10000
#define NFEAT 512
#define NHID 256
#define NCLASS 40
#define MAXDEG 64

// ---------------------------------------------------------------------------
// Pass over dense A once: build ELL adjacency (col indices) + dinv = 1/sqrt(deg+1)
// ---------------------------------------------------------------------------
__global__ __launch_bounds__(256) void build_adj(const float* __restrict__ A,
                                                 int* __restrict__ cols,
                                                 int* __restrict__ deg,
                                                 float* __restrict__ dinv) {
    int row = blockIdx.x;
    __shared__ int cnt;
    if (threadIdx.x == 0) cnt = 0;
    __syncthreads();
    const float4* Arow = (const float4*)(A + (size_t)row * NN);
    int* crow = cols + (size_t)row * MAXDEG;
    for (int q = threadIdx.x; q < NN / 4; q += 256) {
        float4 v = Arow[q];
        if (v.x != 0.f) { int s = atomicAdd(&cnt, 1); if (s < MAXDEG) crow[s] = 4*q+0; }
        if (v.y != 0.f) { int s = atomicAdd(&cnt, 1); if (s < MAXDEG) crow[s] = 4*q+1; }
        if (v.z != 0.f) { int s = atomicAdd(&cnt, 1); if (s < MAXDEG) crow[s] = 4*q+2; }
        if (v.w != 0.f) { int s = atomicAdd(&cnt, 1); if (s < MAXDEG) crow[s] = 4*q+3; }
    }
    __syncthreads();
    if (threadIdx.x == 0) {
        int d = cnt; if (d > MAXDEG) d = MAXDEG;
        deg[row] = d;
        dinv[row] = 1.0f / sqrtf((float)(cnt + 1));
    }
}

// ---------------------------------------------------------------------------
// Wm = 0.25 * (W + W^T)   (folds STEP_SIZE=0.5 and w_star=0.5*(W+W^T))
// ---------------------------------------------------------------------------
__global__ void make_wm(const float* __restrict__ W, float* __restrict__ Wm) {
    int i = blockIdx.x * blockDim.x + threadIdx.x;
    if (i < NHID * NHID) {
        int h = i / NHID, c = i % NHID;
        Wm[i] = 0.25f * (W[h * NHID + c] + W[c * NHID + h]);
    }
}

// ---------------------------------------------------------------------------
// Encoder GEMM: out[r][h] = relu( sum_k x[r][k]*enc_w[h][k] + enc_b[h] )
// A: [M,K] row-major, B: [N,K] row-major (BT layout). Tiled 64x64, BK=32.
// ---------------------------------------------------------------------------
#define BM 64
#define BN 64
#define BK 32
#define LSTR (BM + 4)   // 68 floats; row stride 272B = 17*16 -> float4-aligned

__global__ __launch_bounds__(256) void gemm_enc(const float* __restrict__ Amat,
                                                const float* __restrict__ Bmat,
                                                const float* __restrict__ bias,
                                                float* __restrict__ out,
                                                int M, int K, int Nc) {
    __shared__ float As[BK][LSTR];
    __shared__ float Bs[BK][LSTR];
    int tid = threadIdx.x;
    int m0 = blockIdx.x * BM;
    int n0 = blockIdx.y * BN;
    int ty = tid / 16, tx = tid % 16;
    float acc[4][4];
#pragma unroll
    for (int i = 0; i < 4; ++i)
#pragma unroll
        for (int j = 0; j < 4; ++j) acc[i][j] = 0.f;

    for (int k0 = 0; k0 < K; k0 += BK) {
        // load A tile: 64 rows x 32 k = 512 float4, 2 per thread
#pragma unroll
        for (int l = 0; l < 2; ++l) {
            int idx = tid + l * 256;
            int r = idx / 8, q = idx % 8;
            float4 v = make_float4(0.f, 0.f, 0.f, 0.f);
            if (m0 + r < M) v = *(const float4*)&Amat[(size_t)(m0 + r) * K + k0 + 4 * q];
            As[4*q+0][r] = v.x; As[4*q+1][r] = v.y; As[4*q+2][r] = v.z; As[4*q+3][r] = v.w;
        }
        // load B tile (BT layout): 64 n-rows x 32 k
#pragma unroll
        for (int l = 0; l < 2; ++l) {
            int idx = tid + l * 256;
            int r = idx / 8, q = idx % 8;
            float4 v = *(const float4*)&Bmat[(size_t)(n0 + r) * K + k0 + 4 * q];
            Bs[4*q+0][r] = v.x; Bs[4*q+1][r] = v.y; Bs[4*q+2][r] = v.z; Bs[4*q+3][r] = v.w;
        }
        __syncthreads();
#pragma unroll
        for (int k = 0; k < BK; ++k) {
            float4 a = *(const float4*)&As[k][ty * 4];
            float4 b = *(const float4*)&Bs[k][tx * 4];
            float av[4] = {a.x, a.y, a.z, a.w};
            float bv[4] = {b.x, b.y, b.z, b.w};
#pragma unroll
            for (int i = 0; i < 4; ++i)
#pragma unroll
                for (int j = 0; j < 4; ++j) acc[i][j] = fmaf(av[i], bv[j], acc[i][j]);
        }
        __syncthreads();
    }
#pragma unroll
    for (int i = 0; i < 4; ++i) {
        int r = m0 + ty * 4 + i;
        if (r < M) {
            int c = n0 + tx * 4;
            float4 o;
            o.x = fmaxf(acc[i][0] + bias[c + 0], 0.f);
            o.y = fmaxf(acc[i][1] + bias[c + 1], 0.f);
            o.z = fmaxf(acc[i][2] + bias[c + 2], 0.f);
            o.w = fmaxf(acc[i][3] + bias[c + 3], 0.f);
            *(float4*)&out[(size_t)r * Nc + c] = o;
        }
    }
}

// ---------------------------------------------------------------------------
// SpMM: Y[i] = dinv[i]*( dinv[i]*X[i] + sum_{j in N(i)} dinv[j]*X[j] )
// one wave per row; lane l owns float4 at col 4l (256 cols = 64 lanes * 4)
// ---------------------------------------------------------------------------
__global__ __launch_bounds__(256) void spmm(const int* __restrict__ cols,
                                            const int* __restrict__ deg,
                                            const float* __restrict__ dinv,
                                            const float* __restrict__ X,
                                            float* __restrict__ Y) {
    int wave = threadIdx.x >> 6;
    int lane = threadIdx.x & 63;
    int row = blockIdx.x * 4 + wave;
    if (row >= NN) return;
    int d = deg[row];
    float di = dinv[row];
    const int* crow = cols + (size_t)row * MAXDEG;
    const float4* Xv = (const float4*)X;
    float4 xs = Xv[(size_t)row * 64 + lane];
    float4 acc = make_float4(di * xs.x, di * xs.y, di * xs.z, di * xs.w);
    for (int j = 0; j < d; ++j) {
        int c = crow[j];
        float w = dinv[c];
        float4 xv = Xv[(size_t)c * 64 + lane];
        acc.x = fmaf(w, xv.x, acc.x);
        acc.y = fmaf(w, xv.y, acc.y);
        acc.z = fmaf(w, xv.z, acc.z);
        acc.w = fmaf(w, xv.w, acc.w);
    }
    float4 o = make_float4(di * acc.x, di * acc.y, di * acc.z, di * acc.w);
    ((float4*)Y)[(size_t)row * 64 + lane] = o;
}

// ---------------------------------------------------------------------------
// Layer GEMM: Xn[r][c] = Xc[r][c] + relu( Xc[r][c] + sum_h Y[r][h]*Wm[h][c] )
// B = Wm is [K,N] natural layout.
// ---------------------------------------------------------------------------
__global__ __launch_bounds__(256) void gemm_layer(const float* __restrict__ Y,
                                                  const float* __restrict__ Wm,
                                                  const float* __restrict__ Xc,
                                                  float* __restrict__ Xn,
                                                  int M) {
    const int K = NHID, Nc = NHID;
    __shared__ float As[BK][LSTR];
    __shared__ float Bs[BK][LSTR];
    int tid = threadIdx.x;
    int m0 = blockIdx.x * BM;
    int n0 = blockIdx.y * BN;
    int ty = tid / 16, tx = tid % 16;
    float acc[4][4];
#pragma unroll
    for (int i = 0; i < 4; ++i)
#pragma unroll
        for (int j = 0; j < 4; ++j) acc[i][j] = 0.f;

    for (int k0 = 0; k0 < K; k0 += BK) {
#pragma unroll
        for (int l = 0; l < 2; ++l) {
            int idx = tid + l * 256;
            int r = idx / 8, q = idx % 8;
            float4 v = make_float4(0.f, 0.f, 0.f, 0.f);
            if (m0 + r < M) v = *(const float4*)&Y[(size_t)(m0 + r) * K + k0 + 4 * q];
            As[4*q+0][r] = v.x; As[4*q+1][r] = v.y; As[4*q+2][r] = v.z; As[4*q+3][r] = v.w;
        }
        // B tile: rows k0..k0+31 of Wm, cols n0..n0+63 -> direct (no transpose)
#pragma unroll
        for (int l = 0; l < 2; ++l) {
            int idx = tid + l * 256;
            int kr = idx / 16, cq = idx % 16;
            float4 v = *(const float4*)&Wm[(size_t)(k0 + kr) * Nc + n0 + 4 * cq];
            *(float4*)&Bs[kr][4 * cq] = v;
        }
        __syncthreads();
#pragma unroll
        for (int k = 0; k < BK; ++k) {
            float4 a = *(const float4*)&As[k][ty * 4];
            float4 b = *(const float4*)&Bs[k][tx * 4];
            float av[4] = {a.x, a.y, a.z, a.w};
            float bv[4] = {b.x, b.y, b.z, b.w};
#pragma unroll
            for (int i = 0; i < 4; ++i)
#pragma unroll
                for (int j = 0; j < 4; ++j) acc[i][j] = fmaf(av[i], bv[j], acc[i][j]);
        }
        __syncthreads();
    }
#pragma unroll
    for (int i = 0; i < 4; ++i) {
        int r = m0 + ty * 4 + i;
        if (r < M) {
            int c = n0 + tx * 4;
            float4 xv = *(const float4*)&Xc[(size_t)r * Nc + c];
            float4 o;
            o.x = xv.x + fmaxf(xv.x + acc[i][0], 0.f);
            o.y = xv.y + fmaxf(xv.y + acc[i][1], 0.f);
            o.z = xv.z + fmaxf(xv.z + acc[i][2], 0.f);
            o.w = xv.w + fmaxf(xv.w + acc[i][3], 0.f);
            *(float4*)&Xn[(size_t)r * Nc + c] = o;
        }
    }
}

// ---------------------------------------------------------------------------
// Decoder: out[r][c] = sum_h X[r][h]*dec_w[c][h] + dec_b[c]
// ---------------------------------------------------------------------------
__global__ __launch_bounds__(256) void decoder(const float* __restrict__ X,
                                               const float* __restrict__ dec_w,
                                               const float* __restrict__ dec_b,
                                               float* __restrict__ out) {
    int idx = blockIdx.x * 256 + threadIdx.x;
    if (idx >= NN * NCLASS) return;
    int r = idx / NCLASS, c = idx % NCLASS;
    const float4* xv = (const float4*)(X + (size_t)r * NHID);
    const float4* wv = (const float4*)(dec_w + (size_t)c * NHID);
    float acc = 0.f;
#pragma unroll 8
    for (int q = 0; q < NHID / 4; ++q) {
        float4 a = xv[q], b = wv[q];
        acc = fmaf(a.x, b.x, acc);
        acc = fmaf(a.y, b.y, acc);
        acc = fmaf(a.z, b.z, acc);
        acc = fmaf(a.w, b.w, acc);
    }
    out[idx] = acc + dec_b[c];
}

// ---------------------------------------------------------------------------
extern "C" void kernel_launch(void* const* d_in, const int* in_sizes, int n_in,
                              void* d_out, int out_size, void* d_ws, size_t ws_size,
                              hipStream_t stream) {
    const float* x      = (const float*)d_in[0];
    const float* A      = (const float*)d_in[1];
    const float* enc_w  = (const float*)d_in[2];
    const float* enc_b  = (const float*)d_in[3];
    const float* conv_w = (const float*)d_in[4];
    const float* dec_w  = (const float*)d_in[5];
    const float* dec_b  = (const float*)d_in[6];
    float* out = (float*)d_out;

    char* w = (char*)d_ws;
    int*   cols = (int*)w;            w += (size_t)NN * MAXDEG * sizeof(int);
    int*   deg  = (int*)w;            w += (size_t)NN * sizeof(int);
    float* dinv = (float*)w;          w += (size_t)NN * sizeof(float);
    float* Wm   = (float*)w;          w += (size_t)NHID * NHID * sizeof(float);
    float* Xa   = (float*)w;          w += (size_t)NN * NHID * sizeof(float);
    float* Xb   = (float*)w;          w += (size_t)NN * NHID * sizeof(float);
    float* Yb   = (float*)w;          w += (size_t)NN * NHID * sizeof(float);

    build_adj<<<NN, 256, 0, stream>>>(A, cols, deg, dinv);
    make_wm<<<(NHID * NHID + 255) / 256, 256, 0, stream>>>(conv_w, Wm);

    dim3 ge((NN + BM - 1) / BM, NHID / BN);
    gemm_enc<<<ge, 256, 0, stream>>>(x, enc_w, enc_b, Xa, NN, NFEAT, NHID);

    float* Xcur = Xa;
    float* Xnxt = Xb;
    for (int layer = 0; layer < 4; ++layer) {
        spmm<<<(NN + 3) / 4, 256, 0, stream>>>(cols, deg, dinv, Xcur, Yb);
        gemm_layer<<<ge, 256, 0, stream>>>(Yb, Wm, Xcur, Xnxt, NN);
        float* t = Xcur; Xcur = Xnxt; Xnxt = t;
    }

    decoder<<<(NN * NCLASS + 255) / 256, 256, 0, stream>>>(Xcur, dec_w, dec_b, out);
}

// Round 2
// 804.139 us; speedup vs baseline: 1.0467x; 1.0467x over previous
//
#include <hip/hip_runtime.h>
#include <math.h>

#define NN 10000
#define NFEAT 512
#define NHID 256
#define NCLASS 40
#define MAXDEG 64

typedef __attribute__((ext_vector_type(8))) short short8v;   // 8 bf16 (4 VGPR)
typedef __attribute__((ext_vector_type(4))) float floatx4;   // MFMA acc

static __device__ __forceinline__ unsigned short bf16_rne(float f) {
    unsigned u = __builtin_bit_cast(unsigned, f);
    u += 0x7fffu + ((u >> 16) & 1u);
    return (unsigned short)(u >> 16);
}
static __device__ __forceinline__ float bf16_f32(unsigned short h) {
    unsigned u = ((unsigned)h) << 16;
    return __builtin_bit_cast(float, u);
}

// ---------------------------------------------------------------------------
// build_adj: one WAVE per row; ballot-compaction (no atomics, no branches on
// the hot path). Reads 400 MB of A -> pure HBM-BW bound.
// ---------------------------------------------------------------------------
__global__ __launch_bounds__(256) void build_adj(const float* __restrict__ A,
                                                 int* __restrict__ cols,
                                                 int* __restrict__ deg,
                                                 float* __restrict__ dinv) {
    int wave = threadIdx.x >> 6;
    int lane = threadIdx.x & 63;
    int row = blockIdx.x * 4 + wave;
    if (row >= NN) return;
    const float4* Arow = (const float4*)(A + (size_t)row * NN);
    int* crow = cols + (size_t)row * MAXDEG;
    int off = 0;
    unsigned long long lmask = (lane == 63) ? 0xFFFFFFFFFFFFFFFFull >> 1
                                            : ((1ull << lane) - 1ull);
    for (int q = lane; q < NN / 4; q += 64) {
        float4 v = Arow[q];
        unsigned long long b0 = __ballot(v.x != 0.f);
        unsigned long long b1 = __ballot(v.y != 0.f);
        unsigned long long b2 = __ballot(v.z != 0.f);
        unsigned long long b3 = __ballot(v.w != 0.f);
        if (v.x != 0.f) { int p = off + __popcll(b0 & lmask); if (p < MAXDEG) crow[p] = 4 * q + 0; }
        off += __popcll(b0);
        if (v.y != 0.f) { int p = off + __popcll(b1 & lmask); if (p < MAXDEG) crow[p] = 4 * q + 1; }
        off += __popcll(b1);
        if (v.z != 0.f) { int p = off + __popcll(b2 & lmask); if (p < MAXDEG) crow[p] = 4 * q + 2; }
        off += __popcll(b2);
        if (v.w != 0.f) { int p = off + __popcll(b3 & lmask); if (p < MAXDEG) crow[p] = 4 * q + 3; }
        off += __popcll(b3);
    }
    if (lane == 0) {
        int d = off < MAXDEG ? off : MAXDEG;
        deg[row] = d;
        dinv[row] = 1.0f / sqrtf((float)(off + 1));
    }
}

// ---------------------------------------------------------------------------
// split_f32: v -> bf16 hi + bf16 lo (residual), 4 elems/thread
// ---------------------------------------------------------------------------
__global__ __launch_bounds__(256) void split_f32(const float* __restrict__ src,
                                                 unsigned short* __restrict__ hi,
                                                 unsigned short* __restrict__ lo,
                                                 int n4) {
    int i = blockIdx.x * 256 + threadIdx.x;
    if (i >= n4) return;
    float4 v = ((const float4*)src)[i];
    ushort4 h, l;
    h.x = bf16_rne(v.x); l.x = bf16_rne(v.x - bf16_f32(h.x));
    h.y = bf16_rne(v.y); l.y = bf16_rne(v.y - bf16_f32(h.y));
    h.z = bf16_rne(v.z); l.z = bf16_rne(v.z - bf16_f32(h.z));
    h.w = bf16_rne(v.w); l.w = bf16_rne(v.w - bf16_f32(h.w));
    ((ushort4*)hi)[i] = h;
    ((ushort4*)lo)[i] = l;
}

// ---------------------------------------------------------------------------
// Pack B operands into MFMA B-fragment order:
//   P[((ks*CT + ct)*64 + lane)*8 + j] = B[k][c],
//   k = ks*32 + 8*(lane>>4) + j,  c = ct*16 + (lane&15)
// ---------------------------------------------------------------------------
__global__ __launch_bounds__(256) void pack_layer(const float* __restrict__ W,
                                                  unsigned short* __restrict__ Ph,
                                                  unsigned short* __restrict__ Pl) {
    int idx = blockIdx.x * 256 + threadIdx.x;       // K*N = 256*256
    if (idx >= 256 * 256) return;
    int j = idx & 7, lane = (idx >> 3) & 63;
    int ctks = idx >> 9;                            // ks*16 + ct
    int ct = ctks & 15, ks = ctks >> 4;
    int k = ks * 32 + ((lane >> 4) << 3) + j;
    int c = ct * 16 + (lane & 15);
    float w = 0.25f * (W[k * NHID + c] + W[c * NHID + k]);   // step*0.5*(W+W^T)
    unsigned short h = bf16_rne(w);
    Ph[idx] = h;
    Pl[idx] = bf16_rne(w - bf16_f32(h));
}

__global__ __launch_bounds__(256) void pack_enc(const float* __restrict__ EW,
                                                unsigned short* __restrict__ Ph,
                                                unsigned short* __restrict__ Pl) {
    int idx = blockIdx.x * 256 + threadIdx.x;       // K*N = 512*256
    if (idx >= 512 * 256) return;
    int j = idx & 7, lane = (idx >> 3) & 63;
    int ctks = idx >> 9;                            // ks*16 + ct  (16 ks, 16 ct)
    int ct = ctks & 15, ks = ctks >> 4;
    int k = ks * 32 + ((lane >> 4) << 3) + j;
    int c = ct * 16 + (lane & 15);                  // c == h (output unit)
    float w = EW[c * NFEAT + k];                    // B[k][h] = enc_w[h][k]
    unsigned short h = bf16_rne(w);
    Ph[idx] = h;
    Pl[idx] = bf16_rne(w - bf16_f32(h));
}

__global__ __launch_bounds__(256) void pack_dec(const float* __restrict__ DW,
                                                unsigned short* __restrict__ Ph,
                                                unsigned short* __restrict__ Pl) {
    int idx = blockIdx.x * 256 + threadIdx.x;       // K*Npad = 256*48
    if (idx >= 256 * 48) return;
    int j = idx & 7, lane = (idx >> 3) & 63;
    int ctks = idx >> 9;                            // 0..23 : ks*3 + ct
    int ct = ctks % 3, ks = ctks / 3;
    int k = ks * 32 + ((lane >> 4) << 3) + j;
    int c = ct * 16 + (lane & 15);
    float w = (c < NCLASS) ? DW[c * NHID + k] : 0.f; // B[k][c] = dec_w[c][k]
    unsigned short h = bf16_rne(w);
    Ph[idx] = h;
    Pl[idx] = bf16_rne(w - bf16_f32(h));
}

// ---------------------------------------------------------------------------
// MFMA GEMM (bf16x3 split emulating f32): out = A*B [+epilogue]
// A: [M,K] as bf16 hi/lo row-major.  B: packed fragments (see pack_*).
// Block = 256 thr = 4 waves; wave computes 16 rows x NT*16 cols; K unrolled.
// EPI: 0 = enc (relu(+bias)), 1 = layer (x + relu(x+acc), opt. split-out),
//      2 = dec (+bias, col guard NCLASS)
// ---------------------------------------------------------------------------
template <int K, int NTOT, int NT, int EPI>
__global__ __launch_bounds__(256) void mfma_gemm(const unsigned short* __restrict__ Ah,
                                                 const unsigned short* __restrict__ Al,
                                                 const unsigned short* __restrict__ Ph,
                                                 const unsigned short* __restrict__ Pl,
                                                 const float* __restrict__ aux,
                                                 float* __restrict__ out,
                                                 unsigned short* __restrict__ oh,
                                                 unsigned short* __restrict__ ol,
                                                 int wsplit) {
    int tid = threadIdx.x;
    int wave = tid >> 6, lane = tid & 63;
    int rowA = blockIdx.x * 64 + wave * 16 + (lane & 15);
    if (rowA >= NN) rowA = NN - 1;                  // clamped loads, guarded stores
    int ct0 = blockIdx.y * NT;
    int koff = (lane >> 4) << 3;

    floatx4 acc[NT];
#pragma unroll
    for (int t = 0; t < NT; ++t) acc[t] = (floatx4){0.f, 0.f, 0.f, 0.f};

#pragma unroll
    for (int ks = 0; ks < K / 32; ++ks) {
        short8v a_h = *(const short8v*)(Ah + (size_t)rowA * K + ks * 32 + koff);
        short8v a_l = *(const short8v*)(Al + (size_t)rowA * K + ks * 32 + koff);
        const unsigned short* bph = Ph + ((size_t)(ks * NTOT + ct0) * 64 + lane) * 8;
        const unsigned short* bpl = Pl + ((size_t)(ks * NTOT + ct0) * 64 + lane) * 8;
#pragma unroll
        for (int t = 0; t < NT; ++t) {
            short8v b_h = *(const short8v*)(bph + t * 512);
            short8v b_l = *(const short8v*)(bpl + t * 512);
            acc[t] = __builtin_amdgcn_mfma_f32_16x16x32_bf16(a_h, b_h, acc[t], 0, 0, 0);
            acc[t] = __builtin_amdgcn_mfma_f32_16x16x32_bf16(a_l, b_h, acc[t], 0, 0, 0);
            acc[t] = __builtin_amdgcn_mfma_f32_16x16x32_bf16(a_h, b_l, acc[t], 0, 0, 0);
        }
    }

    // D layout: col = lane&15, row = 4*(lane>>4) + reg   [m89-verified]
    int rbase = blockIdx.x * 64 + wave * 16 + ((lane >> 4) << 2);
    int cbase = ct0 * 16 + (lane & 15);
#pragma unroll
    for (int t = 0; t < NT; ++t) {
        int c = cbase + t * 16;
#pragma unroll
        for (int i = 0; i < 4; ++i) {
            int r = rbase + i;
            if (r < NN) {
                float v = acc[t][i];
                if (EPI == 0) {
                    out[(size_t)r * (NTOT * 16) + c] = fmaxf(v + aux[c], 0.f);
                } else if (EPI == 1) {
                    float xv = aux[(size_t)r * NHID + c];
                    float o = xv + fmaxf(xv + v, 0.f);
                    out[(size_t)r * NHID + c] = o;
                    if (wsplit) {
                        unsigned short h = bf16_rne(o);
                        oh[(size_t)r * NHID + c] = h;
                        ol[(size_t)r * NHID + c] = bf16_rne(o - bf16_f32(h));
                    }
                } else {
                    if (c < NCLASS) out[(size_t)r * NCLASS + c] = v + aux[c];
                }
            }
        }
    }
}

// ---------------------------------------------------------------------------
// SpMM: Y[i] = dinv[i]*( dinv[i]*X[i] + sum_{j in N(i)} dinv[j]*X[j] )
// one wave per row; emits bf16 hi/lo split of Y (A-operand of layer GEMM)
// ---------------------------------------------------------------------------
__global__ __launch_bounds__(256) void spmm(const int* __restrict__ cols,
                                            const int* __restrict__ deg,
                                            const float* __restrict__ dinv,
                                            const float* __restrict__ X,
                                            unsigned short* __restrict__ Yh,
                                            unsigned short* __restrict__ Yl) {
    int wave = threadIdx.x >> 6;
    int lane = threadIdx.x & 63;
    int row = blockIdx.x * 4 + wave;
    if (row >= NN) return;
    int d = deg[row];
    float di = dinv[row];
    const int* crow = cols + (size_t)row * MAXDEG;
    const float4* Xv = (const float4*)X;
    float4 xs = Xv[(size_t)row * 64 + lane];
    float4 acc = make_float4(di * xs.x, di * xs.y, di * xs.z, di * xs.w);
    for (int j = 0; j < d; ++j) {
        int c = crow[j];
        float w = dinv[c];
        float4 xv = Xv[(size_t)c * 64 + lane];
        acc.x = fmaf(w, xv.x, acc.x);
        acc.y = fmaf(w, xv.y, acc.y);
        acc.z = fmaf(w, xv.z, acc.z);
        acc.w = fmaf(w, xv.w, acc.w);
    }
    float4 o = make_float4(di * acc.x, di * acc.y, di * acc.z, di * acc.w);
    ushort4 h, l;
    h.x = bf16_rne(o.x); l.x = bf16_rne(o.x - bf16_f32(h.x));
    h.y = bf16_rne(o.y); l.y = bf16_rne(o.y - bf16_f32(h.y));
    h.z = bf16_rne(o.z); l.z = bf16_rne(o.z - bf16_f32(h.z));
    h.w = bf16_rne(o.w); l.w = bf16_rne(o.w - bf16_f32(h.w));
    ((ushort4*)Yh)[(size_t)row * 64 + lane] = h;
    ((ushort4*)Yl)[(size_t)row * 64 + lane] = l;
}

// ---------------------------------------------------------------------------
extern "C" void kernel_launch(void* const* d_in, const int* in_sizes, int n_in,
                              void* d_out, int out_size, void* d_ws, size_t ws_size,
                              hipStream_t stream) {
    const float* x      = (const float*)d_in[0];
    const float* A      = (const float*)d_in[1];
    const float* enc_w  = (const float*)d_in[2];
    const float* enc_b  = (const float*)d_in[3];
    const float* conv_w = (const float*)d_in[4];
    const float* dec_w  = (const float*)d_in[5];
    const float* dec_b  = (const float*)d_in[6];
    float* out = (float*)d_out;

    char* w = (char*)d_ws;
    auto alloc = [&](size_t bytes) {
        char* p = w;
        w += (bytes + 255) & ~(size_t)255;
        return p;
    };
    int*            cols = (int*)alloc((size_t)NN * MAXDEG * 4);
    int*            deg  = (int*)alloc((size_t)NN * 4);
    float*          dinv = (float*)alloc((size_t)NN * 4);
    unsigned short* xh   = (unsigned short*)alloc((size_t)NN * NFEAT * 2);
    unsigned short* xl   = (unsigned short*)alloc((size_t)NN * NFEAT * 2);
    unsigned short* PEh  = (unsigned short*)alloc((size_t)NFEAT * NHID * 2);
    unsigned short* PEl  = (unsigned short*)alloc((size_t)NFEAT * NHID * 2);
    unsigned short* PWh  = (unsigned short*)alloc((size_t)NHID * NHID * 2);
    unsigned short* PWl  = (unsigned short*)alloc((size_t)NHID * NHID * 2);
    unsigned short* PDh  = (unsigned short*)alloc((size_t)NHID * 48 * 2);
    unsigned short* PDl  = (unsigned short*)alloc((size_t)NHID * 48 * 2);
    float*          Xa   = (float*)alloc((size_t)NN * NHID * 4);
    float*          Xb   = (float*)alloc((size_t)NN * NHID * 4);
    unsigned short* Yh   = (unsigned short*)alloc((size_t)NN * NHID * 2);
    unsigned short* Yl   = (unsigned short*)alloc((size_t)NN * NHID * 2);
    unsigned short* Xfh  = (unsigned short*)alloc((size_t)NN * NHID * 2);
    unsigned short* Xfl  = (unsigned short*)alloc((size_t)NN * NHID * 2);

    build_adj<<<(NN + 3) / 4, 256, 0, stream>>>(A, cols, deg, dinv);
    split_f32<<<(NN * NFEAT / 4 + 255) / 256, 256, 0, stream>>>(x, xh, xl, NN * NFEAT / 4);
    pack_enc<<<(NFEAT * NHID + 255) / 256, 256, 0, stream>>>(enc_w, PEh, PEl);
    pack_layer<<<(NHID * NHID + 255) / 256, 256, 0, stream>>>(conv_w, PWh, PWl);
    pack_dec<<<(NHID * 48 + 255) / 256, 256, 0, stream>>>(dec_w, PDh, PDl);

    dim3 g2((NN + 63) / 64, 2);
    // encoder: X = relu(x @ enc_w^T + b), K=512, N=256
    mfma_gemm<NFEAT, 16, 8, 0><<<g2, 256, 0, stream>>>(xh, xl, PEh, PEl, enc_b, Xa,
                                                       nullptr, nullptr, 0);
    float* Xcur = Xa;
    float* Xnxt = Xb;
    for (int layer = 0; layer < 4; ++layer) {
        spmm<<<(NN + 3) / 4, 256, 0, stream>>>(cols, deg, dinv, Xcur, Yh, Yl);
        mfma_gemm<NHID, 16, 8, 1><<<g2, 256, 0, stream>>>(Yh, Yl, PWh, PWl, Xcur, Xnxt,
                                                          Xfh, Xfl, layer == 3 ? 1 : 0);
        float* t = Xcur; Xcur = Xnxt; Xnxt = t;
    }
    dim3 g1((NN + 63) / 64, 1);
    mfma_gemm<NHID, 3, 3, 2><<<g1, 256, 0, stream>>>(Xfh, Xfl, PDh, PDl, dec_b, out,
                                                     nullptr, nullptr, 0);
}